// Round 3
// baseline (273.414 us; speedup 1.0000x reference)
//
#include <hip/hip_runtime.h>

typedef __attribute__((ext_vector_type(8))) short short8;
typedef __attribute__((ext_vector_type(4))) float f32x4;

#define AS3P(x) ((__attribute__((address_space(3))) void*)(x))
#define AS1P(x) ((const __attribute__((address_space(1))) void*)(x))

__device__ __forceinline__ unsigned short f2bf(float f) {
    unsigned int u = __float_as_uint(f);
    u += 0x7fffu + ((u >> 16) & 1u);   // RNE
    return (unsigned short)(u >> 16);
}
__device__ __forceinline__ float bf2f(unsigned short b) {
    return __uint_as_float(((unsigned int)b) << 16);
}
__device__ __forceinline__ float waveReduceSum(float v) {
    #pragma unroll
    for (int off = 32; off; off >>= 1) v += __shfl_xor(v, off, 64);
    return v;
}

// ---------------- small prep kernels ----------------

__global__ void k_norm_protos(const float* __restrict__ proto, float* __restrict__ protos_n) {
    int w = threadIdx.x >> 6, l = threadIdx.x & 63;
    float v = proto[w * 64 + l];
    float ss = waveReduceSum(v * v);
    float inv = 1.f / fmaxf(sqrtf(ss), 1e-12f);
    protos_n[w * 64 + l] = v * inv;
}

__global__ __launch_bounds__(256) void k_prep_items(const float* __restrict__ item_emb,
                                                    const float* __restrict__ protos_n,
                                                    float* __restrict__ items_n,
                                                    float* __restrict__ cates,
                                                    float* __restrict__ catesT) {
    __shared__ float sp[256];
    int tid = threadIdx.x;
    sp[tid] = protos_n[tid];
    __syncthreads();
    int i = blockIdx.x * 256 + tid;
    const float4* row = (const float4*)(item_emb + (size_t)i * 64);
    float4 f[16];
    float ss = 0.f;
    #pragma unroll
    for (int q = 0; q < 16; ++q) {
        f[q] = row[q];
        ss += f[q].x * f[q].x + f[q].y * f[q].y + f[q].z * f[q].z + f[q].w * f[q].w;
    }
    float inv = 1.f / fmaxf(sqrtf(ss), 1e-12f);
    float dots[4] = {0.f, 0.f, 0.f, 0.f};
    float4* on = (float4*)(items_n + (size_t)i * 64);
    #pragma unroll
    for (int q = 0; q < 16; ++q) {
        f[q].x *= inv; f[q].y *= inv; f[q].z *= inv; f[q].w *= inv;
        on[q] = f[q];
        #pragma unroll
        for (int k = 0; k < 4; ++k) {
            dots[k] += f[q].x * sp[k * 64 + q * 4 + 0] + f[q].y * sp[k * 64 + q * 4 + 1]
                     + f[q].z * sp[k * 64 + q * 4 + 2] + f[q].w * sp[k * 64 + q * 4 + 3];
        }
    }
    float m = fmaxf(fmaxf(dots[0], dots[1]), fmaxf(dots[2], dots[3]));
    float e0 = expf(dots[0] - m), e1 = expf(dots[1] - m), e2 = expf(dots[2] - m), e3 = expf(dots[3] - m);
    float is = 1.f / (e0 + e1 + e2 + e3);
    float4 c; c.x = e0 * is; c.y = e1 * is; c.z = e2 * is; c.w = e3 * is;
    *(float4*)(cates + (size_t)i * 4) = c;
    catesT[0 * 8192 + i] = c.x;
    catesT[1 * 8192 + i] = c.y;
    catesT[2 * 8192 + i] = c.z;
    catesT[3 * 8192 + i] = c.w;
}

// streaming f32 -> bf16 (8 elements/thread) — used for enc_w only
__global__ __launch_bounds__(256) void k_cast_bf16_x8(const float* __restrict__ in,
                                                      unsigned short* __restrict__ out) {
    size_t i = ((size_t)blockIdx.x * 256 + threadIdx.x) * 8;
    float4 a = *(const float4*)(in + i);
    float4 b = *(const float4*)(in + i + 4);
    uint4 pk;
    pk.x = (unsigned int)f2bf(a.x) | ((unsigned int)f2bf(a.y) << 16);
    pk.y = (unsigned int)f2bf(a.z) | ((unsigned int)f2bf(a.w) << 16);
    pk.z = (unsigned int)f2bf(b.x) | ((unsigned int)f2bf(b.y) << 16);
    pk.w = (unsigned int)f2bf(b.z) | ((unsigned int)f2bf(b.w) << 16);
    *(uint4*)(out + i) = pk;
}

// cast rating -> bf16, and compute inv4[b][k] = 1/max(||rating[b] * catesT[k]||, eps)
__global__ __launch_bounds__(256) void k_cast_rating(const float* __restrict__ rating,
                                                     const float* __restrict__ catesT,
                                                     unsigned short* __restrict__ rating_bf,
                                                     float* __restrict__ inv4) {
    int b = blockIdx.x, tid = threadIdx.x;
    const float* row = rating + (size_t)b * 8192;
    float s0 = 0.f, s1 = 0.f, s2 = 0.f, s3 = 0.f;
    #pragma unroll
    for (int j = 0; j < 8; ++j) {
        int i4 = tid + j * 256;
        float4 r = *(const float4*)(row + i4 * 4);
        ushort4 pk;
        pk.x = f2bf(r.x); pk.y = f2bf(r.y); pk.z = f2bf(r.z); pk.w = f2bf(r.w);
        *(ushort4*)(rating_bf + (size_t)b * 8192 + i4 * 4) = pk;
        float4 c0 = *(const float4*)(catesT + 0 * 8192 + i4 * 4);
        float4 c1 = *(const float4*)(catesT + 1 * 8192 + i4 * 4);
        float4 c2 = *(const float4*)(catesT + 2 * 8192 + i4 * 4);
        float4 c3 = *(const float4*)(catesT + 3 * 8192 + i4 * 4);
        float px, py, pz, pw;
        px = r.x * c0.x; py = r.y * c0.y; pz = r.z * c0.z; pw = r.w * c0.w;
        s0 += px * px + py * py + pz * pz + pw * pw;
        px = r.x * c1.x; py = r.y * c1.y; pz = r.z * c1.z; pw = r.w * c1.w;
        s1 += px * px + py * py + pz * pz + pw * pw;
        px = r.x * c2.x; py = r.y * c2.y; pz = r.z * c2.z; pw = r.w * c2.w;
        s2 += px * px + py * py + pz * pz + pw * pw;
        px = r.x * c3.x; py = r.y * c3.y; pz = r.z * c3.z; pw = r.w * c3.w;
        s3 += px * px + py * py + pz * pz + pw * pw;
    }
    s0 = waveReduceSum(s0); s1 = waveReduceSum(s1);
    s2 = waveReduceSum(s2); s3 = waveReduceSum(s3);
    __shared__ float sred[4][4];
    if ((tid & 63) == 0) {
        int w = tid >> 6;
        sred[w][0] = s0; sred[w][1] = s1; sred[w][2] = s2; sred[w][3] = s3;
    }
    __syncthreads();
    if (tid < 4) {
        float ss = sred[0][tid] + sred[1][tid] + sred[2][tid] + sred[3][tid];
        inv4[b * 4 + tid] = 1.f / fmaxf(sqrtf(ss), 1e-12f);
    }
}

// ---------------- GEMM1: A = adj (f32, reg-staged + converted), side-writes adj_bf ----------------
// C partials (bf16) [z][8192][128] = adj[M x Kslice] * B^T ; B = encw [128][8192] bf16
__global__ __launch_bounds__(256) void k_gemm_f32A(const float* __restrict__ A,
                                                   const unsigned short* __restrict__ B,
                                                   unsigned short* __restrict__ Cout,
                                                   unsigned short* __restrict__ Abf,
                                                   int ksplit) {
    __shared__ unsigned short lA[128 * 64];
    __shared__ unsigned short lB[128 * 64];
    int tid = threadIdx.x;
    int lane = tid & 63;
    int w = tid >> 6;
    int wr = w >> 1, wc = w & 1;
    int mBase = blockIdx.y * 128;
    int Kbeg = blockIdx.z * ksplit;
    int Kend = Kbeg + ksplit;

    f32x4 acc[4][4] = {};

    const float* Ablk = A + (size_t)mBase * 8192;
    int srow = tid >> 3;
    int scg = (tid & 7) ^ (srow & 7);
    char* ldsB_w = (char*)lB + w * 1024;

    for (int k0 = Kbeg; k0 < Kend; k0 += 64) {
        float4 av[4][2];
        #pragma unroll
        for (int it = 0; it < 4; ++it) {
            int sid = it * 256 + tid;
            int row = sid >> 3, cg = sid & 7;
            const float* ga = Ablk + (size_t)row * 8192 + k0 + cg * 8;
            av[it][0] = *(const float4*)ga;
            av[it][1] = *(const float4*)(ga + 4);
        }
        __syncthreads();
        #pragma unroll
        for (int it = 0; it < 4; ++it) {
            const unsigned short* gb = B + (size_t)(it * 32 + srow) * 8192 + k0 + scg * 8;
            __builtin_amdgcn_global_load_lds(AS1P(gb), AS3P(ldsB_w + it * 4096), 16, 0, 0);
        }
        #pragma unroll
        for (int it = 0; it < 4; ++it) {
            int sid = it * 256 + tid;
            int row = sid >> 3, cg = sid & 7;
            uint4 pk;
            pk.x = (unsigned int)f2bf(av[it][0].x) | ((unsigned int)f2bf(av[it][0].y) << 16);
            pk.y = (unsigned int)f2bf(av[it][0].z) | ((unsigned int)f2bf(av[it][0].w) << 16);
            pk.z = (unsigned int)f2bf(av[it][1].x) | ((unsigned int)f2bf(av[it][1].y) << 16);
            pk.w = (unsigned int)f2bf(av[it][1].z) | ((unsigned int)f2bf(av[it][1].w) << 16);
            *(uint4*)((char*)lA + row * 128 + ((cg ^ (row & 7)) * 16)) = pk;
            *(uint4*)(Abf + (size_t)(mBase + row) * 8192 + k0 + cg * 8) = pk;
        }
        __syncthreads();
        #pragma unroll
        for (int kk = 0; kk < 2; ++kk) {
            short8 af[4], bfr[4];
            #pragma unroll
            for (int i = 0; i < 4; ++i) {
                int rowa = wr * 64 + i * 16 + (lane & 15);
                int slot = kk * 4 + (lane >> 4);
                af[i] = *(const short8*)((const char*)lA + rowa * 128 + ((slot ^ (rowa & 7)) * 16));
                int rowb = wc * 64 + i * 16 + (lane & 15);
                bfr[i] = *(const short8*)((const char*)lB + rowb * 128 + ((slot ^ (rowb & 7)) * 16));
            }
            #pragma unroll
            for (int i = 0; i < 4; ++i)
                #pragma unroll
                for (int j = 0; j < 4; ++j)
                    acc[i][j] = __builtin_amdgcn_mfma_f32_16x16x32_bf16(af[i], bfr[j], acc[i][j], 0, 0, 0);
        }
    }

    unsigned short* outP = Cout + (size_t)blockIdx.z * 8192 * 128;
    #pragma unroll
    for (int i = 0; i < 4; ++i) {
        int rbase = mBase + wr * 64 + i * 16 + (lane >> 4) * 4;
        #pragma unroll
        for (int j = 0; j < 4; ++j) {
            int col = wc * 64 + j * 16 + (lane & 15);
            #pragma unroll
            for (int r = 0; r < 4; ++r)
                outP[(size_t)(rbase + r) * 128 + col] = f2bf(acc[i][j][r]);
        }
    }
}

// ---------------- MFMA GEMM (bf16 A/B via global_load_lds), bf16 split-K partials ----------------
__global__ __launch_bounds__(256) void k_gemm_part(const unsigned short* __restrict__ A,
                                                   const unsigned short* __restrict__ B,
                                                   unsigned short* __restrict__ Cout,
                                                   int M, int ksplit, int lda, int ldb, int ldc) {
    __shared__ unsigned short lA[128 * 64];
    __shared__ unsigned short lB[128 * 64];
    int tid = threadIdx.x;
    int lane = tid & 63;
    int w = tid >> 6;
    int wr = w >> 1, wc = w & 1;
    int mBase = blockIdx.y * 128;
    int nBase = blockIdx.x * 128;
    int Kbeg = blockIdx.z * ksplit;
    int Kend = Kbeg + ksplit;

    f32x4 acc[4][4] = {};

    const unsigned short* Ablk = A + (size_t)mBase * lda;
    const unsigned short* Bblk = B + (size_t)nBase * ldb;
    int srow = tid >> 3;
    int scg = (tid & 7) ^ (srow & 7);
    char* ldsA_w = (char*)lA + w * 1024;
    char* ldsB_w = (char*)lB + w * 1024;

    for (int k0 = Kbeg; k0 < Kend; k0 += 64) {
        __syncthreads();
        #pragma unroll
        for (int it = 0; it < 4; ++it) {
            const unsigned short* ga = Ablk + (size_t)(it * 32 + srow) * lda + k0 + scg * 8;
            __builtin_amdgcn_global_load_lds(AS1P(ga), AS3P(ldsA_w + it * 4096), 16, 0, 0);
            const unsigned short* gb = Bblk + (size_t)(it * 32 + srow) * ldb + k0 + scg * 8;
            __builtin_amdgcn_global_load_lds(AS1P(gb), AS3P(ldsB_w + it * 4096), 16, 0, 0);
        }
        __syncthreads();
        #pragma unroll
        for (int kk = 0; kk < 2; ++kk) {
            short8 af[4], bfr[4];
            #pragma unroll
            for (int i = 0; i < 4; ++i) {
                int rowa = wr * 64 + i * 16 + (lane & 15);
                int slot = kk * 4 + (lane >> 4);
                af[i] = *(const short8*)((const char*)lA + rowa * 128 + ((slot ^ (rowa & 7)) * 16));
                int rowb = wc * 64 + i * 16 + (lane & 15);
                bfr[i] = *(const short8*)((const char*)lB + rowb * 128 + ((slot ^ (rowb & 7)) * 16));
            }
            #pragma unroll
            for (int i = 0; i < 4; ++i)
                #pragma unroll
                for (int j = 0; j < 4; ++j)
                    acc[i][j] = __builtin_amdgcn_mfma_f32_16x16x32_bf16(af[i], bfr[j], acc[i][j], 0, 0, 0);
        }
    }

    unsigned short* outP = Cout + (size_t)blockIdx.z * M * ldc;
    #pragma unroll
    for (int i = 0; i < 4; ++i) {
        int rbase = mBase + wr * 64 + i * 16 + (lane >> 4) * 4;
        #pragma unroll
        for (int j = 0; j < 4; ++j) {
            int col = nBase + wc * 64 + j * 16 + (lane & 15);
            #pragma unroll
            for (int r = 0; r < 4; ++r)
                outP[(size_t)(rbase + r) * ldc + col] = f2bf(acc[i][j][r]);
        }
    }
}

// sum 8 bf16 partials [sp][8192][128] over sp for a 64-row tile, transpose, store bf16 W1T[o][n]
__global__ __launch_bounds__(256) void k_reduce_T8(const unsigned short* __restrict__ part,
                                                   unsigned short* __restrict__ outT) {
    __shared__ float t[64 * 129];
    int m0 = blockIdx.x * 64;
    int tid = threadIdx.x;
    #pragma unroll
    for (int j = 0; j < 4; ++j) {
        int f = tid + j * 256;             // uint4 (8-elem) chunk within 64x128 tile
        int m = f >> 4, o = (f & 15) * 8;
        float a[8] = {0.f,0.f,0.f,0.f,0.f,0.f,0.f,0.f};
        #pragma unroll
        for (int sp = 0; sp < 8; ++sp) {
            const unsigned short* p = part + (size_t)sp * 8192 * 128 + (size_t)(m0 + m) * 128 + o;
            uint4 v = *(const uint4*)p;
            a[0] += bf2f((unsigned short)(v.x & 0xffff)); a[1] += bf2f((unsigned short)(v.x >> 16));
            a[2] += bf2f((unsigned short)(v.y & 0xffff)); a[3] += bf2f((unsigned short)(v.y >> 16));
            a[4] += bf2f((unsigned short)(v.z & 0xffff)); a[5] += bf2f((unsigned short)(v.z >> 16));
            a[6] += bf2f((unsigned short)(v.w & 0xffff)); a[7] += bf2f((unsigned short)(v.w >> 16));
        }
        #pragma unroll
        for (int e = 0; e < 8; ++e) t[m * 129 + o + e] = a[e];
    }
    __syncthreads();
    #pragma unroll
    for (int j = 0; j < 16; ++j) {
        int idx = tid + j * 256;
        int o = idx >> 5, mp = idx & 31;
        float v0 = t[(mp * 2 + 0) * 129 + o];
        float v1 = t[(mp * 2 + 1) * 129 + o];
        unsigned int pk = (unsigned int)f2bf(v0) | ((unsigned int)f2bf(v1) << 16);
        *(unsigned int*)(outT + (size_t)o * 8192 + m0 + mp * 2) = pk;
    }
}

// same reduce, but epilogue builds G[k*128+o][n] = bf16(cates[k][n] * 0.5*(W2[n][o]+enc_w[o][n]))
__global__ __launch_bounds__(256) void k_reduce_TG8(const unsigned short* __restrict__ part,
                                                    const float* __restrict__ enc_w,
                                                    const float* __restrict__ catesT,
                                                    unsigned short* __restrict__ G) {
    __shared__ float t[64 * 129];
    int m0 = blockIdx.x * 64;
    int tid = threadIdx.x;
    #pragma unroll
    for (int j = 0; j < 4; ++j) {
        int f = tid + j * 256;
        int m = f >> 4, o = (f & 15) * 8;
        float a[8] = {0.f,0.f,0.f,0.f,0.f,0.f,0.f,0.f};
        #pragma unroll
        for (int sp = 0; sp < 8; ++sp) {
            const unsigned short* p = part + (size_t)sp * 8192 * 128 + (size_t)(m0 + m) * 128 + o;
            uint4 v = *(const uint4*)p;
            a[0] += bf2f((unsigned short)(v.x & 0xffff)); a[1] += bf2f((unsigned short)(v.x >> 16));
            a[2] += bf2f((unsigned short)(v.y & 0xffff)); a[3] += bf2f((unsigned short)(v.y >> 16));
            a[4] += bf2f((unsigned short)(v.z & 0xffff)); a[5] += bf2f((unsigned short)(v.z >> 16));
            a[6] += bf2f((unsigned short)(v.w & 0xffff)); a[7] += bf2f((unsigned short)(v.w >> 16));
        }
        #pragma unroll
        for (int e = 0; e < 8; ++e) t[m * 129 + o + e] = a[e];
    }
    __syncthreads();
    #pragma unroll
    for (int j = 0; j < 16; ++j) {
        int idx = tid + j * 256;
        int o = idx >> 5, mp = idx & 31;
        int m = m0 + mp * 2;
        float v0 = t[(mp * 2 + 0) * 129 + o];
        float v1 = t[(mp * 2 + 1) * 129 + o];
        v0 = 0.5f * (v0 + enc_w[(size_t)o * 8192 + m + 0]);
        v1 = 0.5f * (v1 + enc_w[(size_t)o * 8192 + m + 1]);
        #pragma unroll
        for (int k = 0; k < 4; ++k) {
            float c0 = catesT[(size_t)k * 8192 + m + 0];
            float c1 = catesT[(size_t)k * 8192 + m + 1];
            unsigned int pk = (unsigned int)f2bf(v0 * c0) | ((unsigned int)f2bf(v1 * c1) << 16);
            *(unsigned int*)(G + (size_t)(k * 128 + o) * 8192 + m) = pk;
        }
    }
}

// sum 16 bf16 h-partials [sp][512][512], scale by inv4, +bias; write mu (normalized) and logvar
__global__ __launch_bounds__(128) void k_reduce_h2(const unsigned short* __restrict__ hpart,
                                                   const float* __restrict__ enc_b,
                                                   const float* __restrict__ inv4,
                                                   float* __restrict__ outp) {
    int r = blockIdx.x;                 // k*512 + b
    int k = r >> 9, b = r & 511;
    int o = threadIdx.x;
    float s = 0.f;
    #pragma unroll
    for (int sp = 0; sp < 16; ++sp)
        s += bf2f(hpart[(size_t)sp * 262144 + (size_t)b * 512 + k * 128 + o]);
    s = s * inv4[b * 4 + k] + enc_b[o];
    const size_t MU0 = (size_t)512 * 8192;
    const size_t LV0 = MU0 + (size_t)2048 * 64;
    if (o < 64) {
        float ss = s * s;
        #pragma unroll
        for (int off = 32; off; off >>= 1) ss += __shfl_xor(ss, off, 64);
        float inv = 1.f / fmaxf(sqrtf(ss), 1e-12f);
        outp[MU0 + (size_t)r * 64 + o] = s * inv;
    } else {
        outp[LV0 + (size_t)r * 64 + (o - 64)] = -s;
    }
}

// logits: 4 batches per block to reuse the items registers
__global__ __launch_bounds__(256) void k_logits(const float* __restrict__ items_n,
                                                const float* __restrict__ cates,
                                                const float* __restrict__ mu,
                                                float* __restrict__ out) {
    __shared__ float smu[4 * 256];
    int tid = threadIdx.x;
    int b0 = blockIdx.y * 4;
    int k = tid >> 6, d = tid & 63;
    #pragma unroll
    for (int j = 0; j < 4; ++j)
        smu[j * 256 + tid] = mu[((size_t)k * 512 + b0 + j) * 64 + d];
    __syncthreads();
    int n = blockIdx.x * 256 + tid;
    float4 iv[16];
    const float4* ivp = (const float4*)(items_n + (size_t)n * 64);
    #pragma unroll
    for (int q = 0; q < 16; ++q) iv[q] = ivp[q];
    float4 c = *(const float4*)(cates + (size_t)n * 4);
    #pragma unroll
    for (int j = 0; j < 4; ++j) {
        const float* sm = smu + j * 256;
        float d0 = 0.f, d1 = 0.f, d2 = 0.f, d3 = 0.f;
        #pragma unroll
        for (int q = 0; q < 16; ++q) {
            float4 x = iv[q];
            d0 += x.x * sm[0 + q * 4] + x.y * sm[0 + q * 4 + 1] + x.z * sm[0 + q * 4 + 2] + x.w * sm[0 + q * 4 + 3];
            d1 += x.x * sm[64 + q * 4] + x.y * sm[64 + q * 4 + 1] + x.z * sm[64 + q * 4 + 2] + x.w * sm[64 + q * 4 + 3];
            d2 += x.x * sm[128 + q * 4] + x.y * sm[128 + q * 4 + 1] + x.z * sm[128 + q * 4 + 2] + x.w * sm[128 + q * 4 + 3];
            d3 += x.x * sm[192 + q * 4] + x.y * sm[192 + q * 4 + 1] + x.z * sm[192 + q * 4 + 2] + x.w * sm[192 + q * 4 + 3];
        }
        float p = expf(d0) * c.x + expf(d1) * c.y + expf(d2) * c.z + expf(d3) * c.w;
        out[(size_t)(b0 + j) * 8192 + n] = logf(p);
    }
}

extern "C" void kernel_launch(void* const* d_in, const int* in_sizes, int n_in,
                              void* d_out, int out_size, void* d_ws, size_t ws_size,
                              hipStream_t stream) {
    const float* rating   = (const float*)d_in[0];   // [512][8192]
    const float* adj      = (const float*)d_in[1];   // [8192][8192]
    const float* item_emb = (const float*)d_in[2];   // [8192][64]
    const float* proto    = (const float*)d_in[3];   // [4][64]
    const float* enc_w    = (const float*)d_in[4];   // [128][8192]
    const float* enc_b    = (const float*)d_in[5];   // [128]
    float* out = (float*)d_out;

    char* ws = (char*)d_ws;
    unsigned short* adj_bf    = (unsigned short*)ws;                      // 128 MB
    unsigned short* part_bf   = adj_bf + (size_t)8192 * 8192;             // 8*8192*128 bf16 = 16 MB
    unsigned short* rating_bf = part_bf + (size_t)8 * 8192 * 128;         // 512*8192 bf16 = 8 MB
    unsigned short* G         = rating_bf + (size_t)512 * 8192;           // 512*8192 bf16 = 8 MB
    unsigned short* W1T       = G + (size_t)512 * 8192;                   // 128*8192 bf16 = 2 MB
    unsigned short* encw      = W1T + (size_t)128 * 8192;                 // 2 MB
    unsigned short* hpart     = encw + (size_t)128 * 8192;                // 16*512*512 bf16 = 8 MB
    float* protos_n = (float*)(hpart + (size_t)16 * 512 * 512);           // 256
    float* items_n  = protos_n + 256;                                     // 8192*64
    float* cates    = items_n + (size_t)8192 * 64;                        // 8192*4
    float* catesT   = cates + (size_t)8192 * 4;                           // 4*8192
    float* inv4     = catesT + (size_t)4 * 8192;                          // 2048

    k_norm_protos<<<1, 256, 0, stream>>>(proto, protos_n);
    k_prep_items<<<32, 256, 0, stream>>>(item_emb, protos_n, items_n, cates, catesT);
    k_cast_bf16_x8<<<512, 256, 0, stream>>>(enc_w, encw);
    k_cast_rating<<<512, 256, 0, stream>>>(rating, catesT, rating_bf, inv4);

    // W1 = adj @ enc_w^T, fused f32->bf16 cast of adj (side-write adj_bf)
    k_gemm_f32A<<<dim3(1, 64, 8), 256, 0, stream>>>(adj, encw, part_bf, adj_bf, 1024);
    k_reduce_T8<<<128, 256, 0, stream>>>(part_bf, W1T);                   // W1T[o][n]

    // W2 = adj @ W1 ; epilogue of reduce builds G = cates * W3
    k_gemm_part<<<dim3(1, 64, 8), 256, 0, stream>>>(adj_bf, W1T, part_bf, 8192, 1024, 8192, 8192, 128);
    k_reduce_TG8<<<128, 256, 0, stream>>>(part_bf, enc_w, catesT, G);

    // C[b][ko] = rating_bf @ G^T  (split-K 16)
    k_gemm_part<<<dim3(4, 4, 16), 256, 0, stream>>>(rating_bf, G, hpart, 512, 512, 8192, 8192, 512);
    k_reduce_h2<<<2048, 128, 0, stream>>>(hpart, enc_b, inv4, out);

    k_logits<<<dim3(32, 128), 256, 0, stream>>>(items_n, cates, out + (size_t)512 * 8192, out);
}

// Round 4
// 207.519 us; speedup vs baseline: 1.3175x; 1.3175x over previous
//
#include <hip/hip_runtime.h>

typedef __attribute__((ext_vector_type(8))) short short8;
typedef __attribute__((ext_vector_type(4))) float f32x4;

#define AS3P(x) ((__attribute__((address_space(3))) void*)(x))
#define AS1P(x) ((const __attribute__((address_space(1))) void*)(x))

__device__ __forceinline__ unsigned short f2bf(float f) {
    unsigned int u = __float_as_uint(f);
    u += 0x7fffu + ((u >> 16) & 1u);   // RNE
    return (unsigned short)(u >> 16);
}
__device__ __forceinline__ float bf2f(unsigned short b) {
    return __uint_as_float(((unsigned int)b) << 16);
}
__device__ __forceinline__ float waveReduceSum(float v) {
    #pragma unroll
    for (int off = 32; off; off >>= 1) v += __shfl_xor(v, off, 64);
    return v;
}

// ---------------- mega prep: adj cast | enc_w cast | items prep (incl proto norm) ----------------
__global__ __launch_bounds__(256) void k_mega(const float* __restrict__ adj,
                                              unsigned short* __restrict__ adj_bf,
                                              const float* __restrict__ enc_w,
                                              unsigned short* __restrict__ encw,
                                              const float* __restrict__ item_emb,
                                              const float* __restrict__ proto,
                                              unsigned short* __restrict__ items_bf,
                                              float* __restrict__ catesT) {
    __shared__ float sp[256];
    int bx = blockIdx.x, tid = threadIdx.x;
    if (bx < 33280) {
        // streaming f32 -> bf16, 8 elems/thread (adj for bx<32768, enc_w after)
        const float* src = (bx < 32768) ? adj : enc_w;
        unsigned short* dst = (bx < 32768) ? adj_bf : encw;
        size_t base = (bx < 32768) ? (size_t)bx : (size_t)(bx - 32768);
        size_t i = (base * 256 + tid) * 8;
        float4 a = *(const float4*)(src + i);
        float4 b = *(const float4*)(src + i + 4);
        uint4 pk;
        pk.x = (unsigned int)f2bf(a.x) | ((unsigned int)f2bf(a.y) << 16);
        pk.y = (unsigned int)f2bf(a.z) | ((unsigned int)f2bf(a.w) << 16);
        pk.z = (unsigned int)f2bf(b.x) | ((unsigned int)f2bf(b.y) << 16);
        pk.w = (unsigned int)f2bf(b.z) | ((unsigned int)f2bf(b.w) << 16);
        *(uint4*)(dst + i) = pk;
        return;
    }
    // ---- items prep ----
    sp[tid] = proto[tid];
    __syncthreads();
    {
        float v = sp[tid];
        float ss = waveReduceSum(v * v);   // wave w == proto row w
        sp[tid] = v * (1.f / fmaxf(sqrtf(ss), 1e-12f));
    }
    __syncthreads();
    int i = (bx - 33280) * 256 + tid;
    const float4* row = (const float4*)(item_emb + (size_t)i * 64);
    float4 f[16];
    float ss = 0.f;
    #pragma unroll
    for (int q = 0; q < 16; ++q) {
        f[q] = row[q];
        ss += f[q].x * f[q].x + f[q].y * f[q].y + f[q].z * f[q].z + f[q].w * f[q].w;
    }
    float inv = 1.f / fmaxf(sqrtf(ss), 1e-12f);
    float dots[4] = {0.f, 0.f, 0.f, 0.f};
    unsigned short* ob = items_bf + (size_t)i * 64;
    #pragma unroll
    for (int q = 0; q < 16; ++q) {
        f[q].x *= inv; f[q].y *= inv; f[q].z *= inv; f[q].w *= inv;
        #pragma unroll
        for (int k = 0; k < 4; ++k) {
            dots[k] += f[q].x * sp[k * 64 + q * 4 + 0] + f[q].y * sp[k * 64 + q * 4 + 1]
                     + f[q].z * sp[k * 64 + q * 4 + 2] + f[q].w * sp[k * 64 + q * 4 + 3];
        }
    }
    #pragma unroll
    for (int q = 0; q < 16; q += 2) {
        uint4 pk;
        pk.x = (unsigned int)f2bf(f[q].x)     | ((unsigned int)f2bf(f[q].y) << 16);
        pk.y = (unsigned int)f2bf(f[q].z)     | ((unsigned int)f2bf(f[q].w) << 16);
        pk.z = (unsigned int)f2bf(f[q + 1].x) | ((unsigned int)f2bf(f[q + 1].y) << 16);
        pk.w = (unsigned int)f2bf(f[q + 1].z) | ((unsigned int)f2bf(f[q + 1].w) << 16);
        *(uint4*)(ob + q * 4) = pk;
    }
    float m = fmaxf(fmaxf(dots[0], dots[1]), fmaxf(dots[2], dots[3]));
    float e0 = expf(dots[0] - m), e1 = expf(dots[1] - m), e2 = expf(dots[2] - m), e3 = expf(dots[3] - m);
    float is = 1.f / (e0 + e1 + e2 + e3);
    catesT[0 * 8192 + i] = e0 * is;
    catesT[1 * 8192 + i] = e1 * is;
    catesT[2 * 8192 + i] = e2 * is;
    catesT[3 * 8192 + i] = e3 * is;
}

// ---------------- MFMA GEMM (bf16 A/B via global_load_lds), bf16 split-K partials ----------------
__global__ __launch_bounds__(256) void k_gemm_part(const unsigned short* __restrict__ A,
                                                   const unsigned short* __restrict__ B,
                                                   unsigned short* __restrict__ Cout,
                                                   int M, int ksplit, int lda, int ldb, int ldc) {
    __shared__ unsigned short lA[128 * 64];
    __shared__ unsigned short lB[128 * 64];
    int tid = threadIdx.x;
    int lane = tid & 63;
    int w = tid >> 6;
    int wr = w >> 1, wc = w & 1;
    int mBase = blockIdx.y * 128;
    int nBase = blockIdx.x * 128;
    int Kbeg = blockIdx.z * ksplit;
    int Kend = Kbeg + ksplit;

    f32x4 acc[4][4] = {};

    const unsigned short* Ablk = A + (size_t)mBase * lda;
    const unsigned short* Bblk = B + (size_t)nBase * ldb;
    int srow = tid >> 3;
    int scg = (tid & 7) ^ (srow & 7);
    char* ldsA_w = (char*)lA + w * 1024;
    char* ldsB_w = (char*)lB + w * 1024;

    for (int k0 = Kbeg; k0 < Kend; k0 += 64) {
        __syncthreads();
        #pragma unroll
        for (int it = 0; it < 4; ++it) {
            const unsigned short* ga = Ablk + (size_t)(it * 32 + srow) * lda + k0 + scg * 8;
            __builtin_amdgcn_global_load_lds(AS1P(ga), AS3P(ldsA_w + it * 4096), 16, 0, 0);
            const unsigned short* gb = Bblk + (size_t)(it * 32 + srow) * ldb + k0 + scg * 8;
            __builtin_amdgcn_global_load_lds(AS1P(gb), AS3P(ldsB_w + it * 4096), 16, 0, 0);
        }
        __syncthreads();
        #pragma unroll
        for (int kk = 0; kk < 2; ++kk) {
            short8 af[4], bfr[4];
            #pragma unroll
            for (int i = 0; i < 4; ++i) {
                int rowa = wr * 64 + i * 16 + (lane & 15);
                int slot = kk * 4 + (lane >> 4);
                af[i] = *(const short8*)((const char*)lA + rowa * 128 + ((slot ^ (rowa & 7)) * 16));
                int rowb = wc * 64 + i * 16 + (lane & 15);
                bfr[i] = *(const short8*)((const char*)lB + rowb * 128 + ((slot ^ (rowb & 7)) * 16));
            }
            #pragma unroll
            for (int i = 0; i < 4; ++i)
                #pragma unroll
                for (int j = 0; j < 4; ++j)
                    acc[i][j] = __builtin_amdgcn_mfma_f32_16x16x32_bf16(af[i], bfr[j], acc[i][j], 0, 0, 0);
        }
    }

    unsigned short* outP = Cout + (size_t)blockIdx.z * M * ldc;
    #pragma unroll
    for (int i = 0; i < 4; ++i) {
        int rbase = mBase + wr * 64 + i * 16 + (lane >> 4) * 4;
        #pragma unroll
        for (int j = 0; j < 4; ++j) {
            int col = nBase + wc * 64 + j * 16 + (lane & 15);
            #pragma unroll
            for (int r = 0; r < 4; ++r)
                outP[(size_t)(rbase + r) * ldc + col] = f2bf(acc[i][j][r]);
        }
    }
}

// bx<128: sum 16 bf16 partials, transpose -> W1T[o][n]   |   bx>=128: rating cast + inv4
__global__ __launch_bounds__(256) void k_red1(const unsigned short* __restrict__ part,
                                              unsigned short* __restrict__ outT,
                                              const float* __restrict__ rating,
                                              const float* __restrict__ catesT,
                                              unsigned short* __restrict__ rating_bf,
                                              float* __restrict__ inv4) {
    __shared__ float t[64 * 129];
    int tid = threadIdx.x;
    if (blockIdx.x < 128) {
        int m0 = blockIdx.x * 64;
        #pragma unroll
        for (int j = 0; j < 4; ++j) {
            int f = tid + j * 256;
            int m = f >> 4, o = (f & 15) * 8;
            float a[8] = {0.f,0.f,0.f,0.f,0.f,0.f,0.f,0.f};
            #pragma unroll
            for (int sp = 0; sp < 16; ++sp) {
                const unsigned short* p = part + (size_t)sp * 8192 * 128 + (size_t)(m0 + m) * 128 + o;
                uint4 v = *(const uint4*)p;
                a[0] += bf2f((unsigned short)(v.x & 0xffff)); a[1] += bf2f((unsigned short)(v.x >> 16));
                a[2] += bf2f((unsigned short)(v.y & 0xffff)); a[3] += bf2f((unsigned short)(v.y >> 16));
                a[4] += bf2f((unsigned short)(v.z & 0xffff)); a[5] += bf2f((unsigned short)(v.z >> 16));
                a[6] += bf2f((unsigned short)(v.w & 0xffff)); a[7] += bf2f((unsigned short)(v.w >> 16));
            }
            #pragma unroll
            for (int e = 0; e < 8; ++e) t[m * 129 + o + e] = a[e];
        }
        __syncthreads();
        #pragma unroll
        for (int j = 0; j < 16; ++j) {
            int idx = tid + j * 256;
            int o = idx >> 5, mp = idx & 31;
            float v0 = t[(mp * 2 + 0) * 129 + o];
            float v1 = t[(mp * 2 + 1) * 129 + o];
            unsigned int pk = (unsigned int)f2bf(v0) | ((unsigned int)f2bf(v1) << 16);
            *(unsigned int*)(outT + (size_t)o * 8192 + m0 + mp * 2) = pk;
        }
        return;
    }
    // rating cast + per-(b,k) norms
    int b = blockIdx.x - 128;
    const float* row = rating + (size_t)b * 8192;
    float s0 = 0.f, s1 = 0.f, s2 = 0.f, s3 = 0.f;
    #pragma unroll
    for (int j = 0; j < 8; ++j) {
        int i4 = tid + j * 256;
        float4 r = *(const float4*)(row + i4 * 4);
        ushort4 pk;
        pk.x = f2bf(r.x); pk.y = f2bf(r.y); pk.z = f2bf(r.z); pk.w = f2bf(r.w);
        *(ushort4*)(rating_bf + (size_t)b * 8192 + i4 * 4) = pk;
        float4 c0 = *(const float4*)(catesT + 0 * 8192 + i4 * 4);
        float4 c1 = *(const float4*)(catesT + 1 * 8192 + i4 * 4);
        float4 c2 = *(const float4*)(catesT + 2 * 8192 + i4 * 4);
        float4 c3 = *(const float4*)(catesT + 3 * 8192 + i4 * 4);
        float px, py, pz, pw;
        px = r.x * c0.x; py = r.y * c0.y; pz = r.z * c0.z; pw = r.w * c0.w;
        s0 += px * px + py * py + pz * pz + pw * pw;
        px = r.x * c1.x; py = r.y * c1.y; pz = r.z * c1.z; pw = r.w * c1.w;
        s1 += px * px + py * py + pz * pz + pw * pw;
        px = r.x * c2.x; py = r.y * c2.y; pz = r.z * c2.z; pw = r.w * c2.w;
        s2 += px * px + py * py + pz * pz + pw * pw;
        px = r.x * c3.x; py = r.y * c3.y; pz = r.z * c3.z; pw = r.w * c3.w;
        s3 += px * px + py * py + pz * pz + pw * pw;
    }
    s0 = waveReduceSum(s0); s1 = waveReduceSum(s1);
    s2 = waveReduceSum(s2); s3 = waveReduceSum(s3);
    if ((tid & 63) == 0) {
        int w = tid >> 6;
        t[w * 4 + 0] = s0; t[w * 4 + 1] = s1; t[w * 4 + 2] = s2; t[w * 4 + 3] = s3;
    }
    __syncthreads();
    if (tid < 4) {
        float ss = t[0 * 4 + tid] + t[1 * 4 + tid] + t[2 * 4 + tid] + t[3 * 4 + tid];
        inv4[b * 4 + tid] = 1.f / fmaxf(sqrtf(ss), 1e-12f);
    }
}

// sum 16 partials; epilogue builds G[k*128+o][n] = bf16(cates[k][n] * 0.5*(W2[n][o]+enc_w[o][n]))
__global__ __launch_bounds__(256) void k_reduce_TG(const unsigned short* __restrict__ part,
                                                   const float* __restrict__ enc_w,
                                                   const float* __restrict__ catesT,
                                                   unsigned short* __restrict__ G) {
    __shared__ float t[64 * 129];
    int m0 = blockIdx.x * 64;
    int tid = threadIdx.x;
    #pragma unroll
    for (int j = 0; j < 4; ++j) {
        int f = tid + j * 256;
        int m = f >> 4, o = (f & 15) * 8;
        float a[8] = {0.f,0.f,0.f,0.f,0.f,0.f,0.f,0.f};
        #pragma unroll
        for (int sp = 0; sp < 16; ++sp) {
            const unsigned short* p = part + (size_t)sp * 8192 * 128 + (size_t)(m0 + m) * 128 + o;
            uint4 v = *(const uint4*)p;
            a[0] += bf2f((unsigned short)(v.x & 0xffff)); a[1] += bf2f((unsigned short)(v.x >> 16));
            a[2] += bf2f((unsigned short)(v.y & 0xffff)); a[3] += bf2f((unsigned short)(v.y >> 16));
            a[4] += bf2f((unsigned short)(v.z & 0xffff)); a[5] += bf2f((unsigned short)(v.z >> 16));
            a[6] += bf2f((unsigned short)(v.w & 0xffff)); a[7] += bf2f((unsigned short)(v.w >> 16));
        }
        #pragma unroll
        for (int e = 0; e < 8; ++e) t[m * 129 + o + e] = a[e];
    }
    __syncthreads();
    #pragma unroll
    for (int j = 0; j < 16; ++j) {
        int idx = tid + j * 256;
        int o = idx >> 5, mp = idx & 31;
        int m = m0 + mp * 2;
        float v0 = t[(mp * 2 + 0) * 129 + o];
        float v1 = t[(mp * 2 + 1) * 129 + o];
        v0 = 0.5f * (v0 + enc_w[(size_t)o * 8192 + m + 0]);
        v1 = 0.5f * (v1 + enc_w[(size_t)o * 8192 + m + 1]);
        #pragma unroll
        for (int k = 0; k < 4; ++k) {
            float c0 = catesT[(size_t)k * 8192 + m + 0];
            float c1 = catesT[(size_t)k * 8192 + m + 1];
            unsigned int pk = (unsigned int)f2bf(v0 * c0) | ((unsigned int)f2bf(v1 * c1) << 16);
            *(unsigned int*)(G + (size_t)(k * 128 + o) * 8192 + m) = pk;
        }
    }
}

// sum 16 bf16 h-partials, scale by inv4, +bias; write mu (f32 + bf16) and logvar
__global__ __launch_bounds__(128) void k_reduce_h2(const unsigned short* __restrict__ hpart,
                                                   const float* __restrict__ enc_b,
                                                   const float* __restrict__ inv4,
                                                   unsigned short* __restrict__ mu_bf,
                                                   float* __restrict__ outp) {
    int r = blockIdx.x;                 // k*512 + b
    int k = r >> 9, b = r & 511;
    int o = threadIdx.x;
    float s = 0.f;
    #pragma unroll
    for (int sp = 0; sp < 16; ++sp)
        s += bf2f(hpart[(size_t)sp * 262144 + (size_t)b * 512 + k * 128 + o]);
    s = s * inv4[b * 4 + k] + enc_b[o];
    const size_t MU0 = (size_t)512 * 8192;
    const size_t LV0 = MU0 + (size_t)2048 * 64;
    if (o < 64) {
        float ss = s * s;
        #pragma unroll
        for (int off = 32; off; off >>= 1) ss += __shfl_xor(ss, off, 64);
        float inv = 1.f / fmaxf(sqrtf(ss), 1e-12f);
        float mv = s * inv;
        outp[MU0 + (size_t)r * 64 + o] = mv;
        mu_bf[(size_t)r * 64 + o] = f2bf(mv);
    } else {
        outp[LV0 + (size_t)r * 64 + (o - 64)] = -s;
    }
}

// MFMA logits: per block 128(b) x 128(n), loop 4 protos; out = log(sum_k exp(z_k . item) * cates_k)
__global__ __launch_bounds__(256) void k_logits_mfma(const unsigned short* __restrict__ mu_bf,
                                                     const unsigned short* __restrict__ items_bf,
                                                     const float* __restrict__ catesT,
                                                     float* __restrict__ out) {
    __shared__ unsigned short lA[128 * 64];
    __shared__ unsigned short lB[128 * 64];
    int tid = threadIdx.x;
    int lane = tid & 63, w = tid >> 6, wr = w >> 1, wc = w & 1;
    int nBase = blockIdx.x * 128, bBase = blockIdx.y * 128;
    int srow = tid >> 3;
    int scg = (tid & 7) ^ (srow & 7);
    char* ldsA_w = (char*)lA + w * 1024;
    char* ldsB_w = (char*)lB + w * 1024;

    #pragma unroll
    for (int it = 0; it < 4; ++it) {
        const unsigned short* gb = items_bf + (size_t)(nBase + it * 32 + srow) * 64 + scg * 8;
        __builtin_amdgcn_global_load_lds(AS1P(gb), AS3P(ldsB_w + it * 4096), 16, 0, 0);
    }

    f32x4 p[4][4] = {};
    for (int k = 0; k < 4; ++k) {
        __syncthreads();   // drains outstanding loads; protects lA overwrite
        #pragma unroll
        for (int it = 0; it < 4; ++it) {
            const unsigned short* ga = mu_bf + (size_t)(k * 512 + bBase + it * 32 + srow) * 64 + scg * 8;
            __builtin_amdgcn_global_load_lds(AS1P(ga), AS3P(ldsA_w + it * 4096), 16, 0, 0);
        }
        __syncthreads();
        f32x4 acc[4][4] = {};
        #pragma unroll
        for (int kk = 0; kk < 2; ++kk) {
            short8 af[4], bfr[4];
            #pragma unroll
            for (int i = 0; i < 4; ++i) {
                int rowa = wr * 64 + i * 16 + (lane & 15);
                int slot = kk * 4 + (lane >> 4);
                af[i] = *(const short8*)((const char*)lA + rowa * 128 + ((slot ^ (rowa & 7)) * 16));
                int rowb = wc * 64 + i * 16 + (lane & 15);
                bfr[i] = *(const short8*)((const char*)lB + rowb * 128 + ((slot ^ (rowb & 7)) * 16));
            }
            #pragma unroll
            for (int i = 0; i < 4; ++i)
                #pragma unroll
                for (int j = 0; j < 4; ++j)
                    acc[i][j] = __builtin_amdgcn_mfma_f32_16x16x32_bf16(af[i], bfr[j], acc[i][j], 0, 0, 0);
        }
        #pragma unroll
        for (int j = 0; j < 4; ++j) {
            int col = nBase + wc * 64 + j * 16 + (lane & 15);
            float c = catesT[(size_t)k * 8192 + col];
            #pragma unroll
            for (int i = 0; i < 4; ++i)
                #pragma unroll
                for (int r = 0; r < 4; ++r)
                    p[i][j][r] += __expf(acc[i][j][r]) * c;
        }
    }
    #pragma unroll
    for (int i = 0; i < 4; ++i) {
        int rbase = bBase + wr * 64 + i * 16 + (lane >> 4) * 4;
        #pragma unroll
        for (int j = 0; j < 4; ++j) {
            int col = nBase + wc * 64 + j * 16 + (lane & 15);
            #pragma unroll
            for (int r = 0; r < 4; ++r)
                out[(size_t)(rbase + r) * 8192 + col] = __logf(p[i][j][r]);
        }
    }
}

extern "C" void kernel_launch(void* const* d_in, const int* in_sizes, int n_in,
                              void* d_out, int out_size, void* d_ws, size_t ws_size,
                              hipStream_t stream) {
    const float* rating   = (const float*)d_in[0];   // [512][8192]
    const float* adj      = (const float*)d_in[1];   // [8192][8192]
    const float* item_emb = (const float*)d_in[2];   // [8192][64]
    const float* proto    = (const float*)d_in[3];   // [4][64]
    const float* enc_w    = (const float*)d_in[4];   // [128][8192]
    const float* enc_b    = (const float*)d_in[5];   // [128]
    float* out = (float*)d_out;

    char* ws = (char*)d_ws;
    unsigned short* adj_bf    = (unsigned short*)ws;                      // 128 MiB
    unsigned short* part_bf   = adj_bf + (size_t)8192 * 8192;             // 16*8192*128 bf16 = 32 MiB
    unsigned short* rating_bf = part_bf + (size_t)16 * 8192 * 128;        // 8 MiB
    unsigned short* G         = rating_bf + (size_t)512 * 8192;           // 8 MiB
    unsigned short* W1T       = G + (size_t)512 * 8192;                   // 2 MiB
    unsigned short* encw      = W1T + (size_t)128 * 8192;                 // 2 MiB
    unsigned short* hpart     = encw + (size_t)128 * 8192;                // 16*512*512 bf16 = 8 MiB
    unsigned short* items_bf  = hpart + (size_t)16 * 512 * 512;           // 1 MiB
    unsigned short* mu_bf     = items_bf + (size_t)8192 * 64;             // 0.25 MiB
    float* catesT = (float*)(mu_bf + (size_t)2048 * 64);                  // 4*8192 f32
    float* inv4   = catesT + (size_t)4 * 8192;                            // 2048 f32

    // prep: adj->bf16 (32768 blk) | enc_w->bf16 (512 blk) | items norm+cates (32 blk)
    k_mega<<<33312, 256, 0, stream>>>(adj, adj_bf, enc_w, encw, item_emb, proto, items_bf, catesT);

    // W1 = adj @ enc_w^T  (split-K 16)
    k_gemm_part<<<dim3(1, 64, 16), 256, 0, stream>>>(adj_bf, encw, part_bf, 8192, 512, 8192, 8192, 128);
    // reduce->W1T (128 blk) | rating cast + inv4 (512 blk)
    k_red1<<<640, 256, 0, stream>>>(part_bf, W1T, rating, catesT, rating_bf, inv4);

    // W2 = adj @ W1 ; epilogue builds G = cates * W3
    k_gemm_part<<<dim3(1, 64, 16), 256, 0, stream>>>(adj_bf, W1T, part_bf, 8192, 512, 8192, 8192, 128);
    k_reduce_TG<<<128, 256, 0, stream>>>(part_bf, enc_w, catesT, G);

    // h = rating_bf @ G^T  (split-K 16)
    k_gemm_part<<<dim3(4, 4, 16), 256, 0, stream>>>(rating_bf, G, hpart, 512, 512, 8192, 8192, 512);
    k_reduce_h2<<<2048, 128, 0, stream>>>(hpart, enc_b, inv4, mu_bf, out);

    k_logits_mfma<<<dim3(64, 4), 256, 0, stream>>>(mu_bf, items_bf, catesT, out);
}